// Round 1
// baseline (2430.021 us; speedup 1.0000x reference)
//
#include <hip/hip_runtime.h>
#include <hip/hip_bf16.h>
#include <stdint.h>

#define BB 64
#define HH 1024
#define VV 50257
#define TT 7
#define GG 3072   // 3*HH

typedef __attribute__((ext_vector_type(8))) short bf16x8;
typedef __attribute__((ext_vector_type(4))) float f32x4;
typedef unsigned short u16;
typedef unsigned int u32;

__device__ __forceinline__ u16 rne_bf16(float f) {
    union { float f; u32 u; } v; v.f = f;
    u32 u = v.u + 0x7FFFu + ((v.u >> 16) & 1u);
    return (u16)(u >> 16);
}
__device__ __forceinline__ float bf16_f32(u16 s) {
    union { u32 u; float f; } v; v.u = ((u32)s) << 16;
    return v.f;
}
// split f into hi (truncated bf16) + lo (rne bf16 of residual); hi+lo == f to ~2^-17|f|
__device__ __forceinline__ void split2(float f, u16 &hi, u16 &lo) {
    union { float f; u32 u; } v; v.f = f;
    union { u32 u; float f; } hv; hv.u = v.u & 0xFFFF0000u;
    hi = (u16)(v.u >> 16);
    lo = rne_bf16(f - hv.f);
}

// ---------------- init: h = encoder_op[0]; e = relu(emb[target[:,0]]) ----------------
__global__ void init_kernel(const int* __restrict__ target, const float* __restrict__ enc,
                            const float* __restrict__ emb,
                            float* __restrict__ h, u16* __restrict__ h_hi, u16* __restrict__ h_lo,
                            u16* __restrict__ e_hi, u16* __restrict__ e_lo) {
    int b = blockIdx.x;
    int x0 = target[b * TT];
    for (int k = threadIdx.x; k < HH; k += blockDim.x) {
        float hv = enc[b * HH + k];
        h[b * HH + k] = hv;
        u16 hh, hl; split2(hv, hh, hl);
        h_hi[b * HH + k] = hh; h_lo[b * HH + k] = hl;
        float e = emb[(size_t)x0 * HH + k];
        e = e > 0.f ? e : 0.f;
        u16 eh, el; split2(e, eh, el);
        e_hi[b * HH + k] = eh; e_lo[b * HH + k] = el;
    }
}

// ---------------- bf16x3 GEMM body: C[m][n] = sum_k A[m][k]*W[n][k] + bias[n] ----------------
// A given pre-split (Ahi/Alo, 64 x 1024 bf16 bits). W fp32 (N x 1024 row-major), split in-reg.
// Block: 256 thr = 4 waves; wave w owns cols [blk*64 + 16w, +16), all 64 rows. K-loop step 32.
__device__ __forceinline__ void gemm_body(
    const u16* __restrict__ Ahi, const u16* __restrict__ Alo,
    const float* __restrict__ W, const float* __restrict__ bias,
    float* __restrict__ C, int N, int ldc)
{
    const int wave = threadIdx.x >> 6;
    const int lane = threadIdx.x & 63;
    const int quad = lane >> 4;
    const int l16  = lane & 15;
    const int col  = blockIdx.x * 64 + wave * 16 + l16;
    const int colc = col < N ? col : N - 1;

    const float* __restrict__ Brow = W + (size_t)colc * HH;
    const int koff = quad * 8;

    f32x4 acc[4];
#pragma unroll
    for (int mt = 0; mt < 4; ++mt) acc[mt] = (f32x4){0.f, 0.f, 0.f, 0.f};

    for (int kb = 0; kb < HH; kb += 32) {
        const float* bp = Brow + kb + koff;
        f32x4 bv0 = *(const f32x4*)(bp);
        f32x4 bv1 = *(const f32x4*)(bp + 4);
        bf16x8 bhi, blo;
#pragma unroll
        for (int j = 0; j < 8; ++j) {
            float f = j < 4 ? bv0[j] : bv1[j - 4];
            union { float f; u32 u; } c; c.f = f;
            union { u32 u; float f; } hf; hf.u = c.u & 0xFFFF0000u;
            bhi[j] = (short)(c.u >> 16);
            blo[j] = (short)rne_bf16(f - hf.f);
        }
#pragma unroll
        for (int mt = 0; mt < 4; ++mt) {
            const size_t aoff = (size_t)(mt * 16 + l16) * HH + kb + koff;
            bf16x8 ahi = *(const bf16x8*)(Ahi + aoff);
            bf16x8 alo = *(const bf16x8*)(Alo + aoff);
            acc[mt] = __builtin_amdgcn_mfma_f32_16x16x32_bf16(ahi, bhi, acc[mt], 0, 0, 0);
            acc[mt] = __builtin_amdgcn_mfma_f32_16x16x32_bf16(alo, bhi, acc[mt], 0, 0, 0);
            acc[mt] = __builtin_amdgcn_mfma_f32_16x16x32_bf16(ahi, blo, acc[mt], 0, 0, 0);
        }
    }

    if (col < N) {
        float bv = bias[col];
#pragma unroll
        for (int mt = 0; mt < 4; ++mt) {
#pragma unroll
            for (int r = 0; r < 4; ++r) {
                int row = mt * 16 + quad * 4 + r;  // batch index (D: col=lane&15, row=quad*4+reg)
                C[(size_t)row * ldc + col] = acc[mt][r] + bv;
            }
        }
    }
}

__global__ __launch_bounds__(256) void gemm_gates_kernel(
    const u16* __restrict__ e_hi, const u16* __restrict__ e_lo,
    const u16* __restrict__ h_hi, const u16* __restrict__ h_lo,
    const float* __restrict__ w_ih, const float* __restrict__ w_hh,
    const float* __restrict__ b_ih, const float* __restrict__ b_hh,
    float* __restrict__ gi, float* __restrict__ gh)
{
    if (blockIdx.y == 0) gemm_body(e_hi, e_lo, w_ih, b_ih, gi, GG, GG);
    else                 gemm_body(h_hi, h_lo, w_hh, b_hh, gh, GG, GG);
}

__global__ __launch_bounds__(256) void gemm_logits_kernel(
    const u16* __restrict__ h_hi, const u16* __restrict__ h_lo,
    const float* __restrict__ lin_w, const float* __restrict__ lin_b,
    float* __restrict__ out_logits /* = out2 + t*V; row stride T*V */)
{
    gemm_body(h_hi, h_lo, lin_w, lin_b, out_logits, VV, TT * VV);
}

// ---------------- GRU gating ----------------
__global__ void gate_kernel(const float* __restrict__ gi, const float* __restrict__ gh,
                            float* __restrict__ h, u16* __restrict__ h_hi, u16* __restrict__ h_lo) {
    int idx = blockIdx.x * blockDim.x + threadIdx.x;   // 0 .. 65535
    int b = idx >> 10, j = idx & 1023;
    float ir = gi[b * GG + j], iz = gi[b * GG + 1024 + j], in_ = gi[b * GG + 2048 + j];
    float hr = gh[b * GG + j], hz = gh[b * GG + 1024 + j], hn = gh[b * GG + 2048 + j];
    float r = 1.f / (1.f + expf(-(ir + hr)));
    float z = 1.f / (1.f + expf(-(iz + hz)));
    float n = tanhf(in_ + r * hn);
    float hold = h[b * HH + j];
    float hnew = (1.f - z) * n + z * hold;
    h[b * HH + j] = hnew;
    u16 hh, hl; split2(hnew, hh, hl);
    h_hi[b * HH + j] = hh; h_lo[b * HH + j] = hl;
}

// ---------------- argmax + logsumexp + gather next embedding ----------------
__global__ __launch_bounds__(256) void argmax_kernel(
    const float* __restrict__ logits_t /* out2 + t*V */, const float* __restrict__ emb,
    int t, float* __restrict__ row_lse, u16* __restrict__ e_hi, u16* __restrict__ e_lo)
{
    __shared__ float sm[256], ss[256];
    __shared__ int sbi[256];
    int b = blockIdx.x, tid = threadIdx.x;
    const float* row = logits_t + (size_t)b * (TT * (size_t)VV);

    float m = -INFINITY, s = 0.f; int bi = 0x7fffffff;
    for (int v = tid; v < VV; v += 256) {
        float x = row[v];
        if (x > m) { s = s * expf(m - x) + 1.f; m = x; bi = v; }
        else       { s += expf(x - m); }
    }
    sm[tid] = m; ss[tid] = s; sbi[tid] = bi;
    __syncthreads();
    for (int off = 128; off > 0; off >>= 1) {
        if (tid < off) {
            float m1 = sm[tid], s1 = ss[tid]; int b1 = sbi[tid];
            float m2 = sm[tid + off], s2 = ss[tid + off]; int b2 = sbi[tid + off];
            float mn = fmaxf(m1, m2);
            float sn = s1 * expf(m1 - mn) + s2 * expf(m2 - mn);
            int bn = (m1 > m2) ? b1 : (m2 > m1) ? b2 : min(b1, b2);
            sm[tid] = mn; ss[tid] = sn; sbi[tid] = bn;
        }
        __syncthreads();
    }
    if (tid == 0) row_lse[b * TT + t] = sm[0] + logf(ss[0]);
    int xi = sbi[0];
    __syncthreads();
    for (int k = tid; k < HH; k += 256) {
        float e = emb[(size_t)xi * HH + k];
        e = e > 0.f ? e : 0.f;
        u16 eh, el; split2(e, eh, el);
        e_hi[b * HH + k] = eh; e_lo[b * HH + k] = el;
    }
}

// ---------------- final log_softmax: out1 = logits - lse ----------------
__global__ void logsoftmax_kernel(const float* __restrict__ out2, const float* __restrict__ row_lse,
                                  float* __restrict__ out1) {
    int row = blockIdx.x;   // b*TT + t
    float lse = row_lse[row];
    const float* src = out2 + (size_t)row * VV;
    float* dst = out1 + (size_t)row * VV;
    for (int v = threadIdx.x; v < VV; v += blockDim.x) dst[v] = src[v] - lse;
}

extern "C" void kernel_launch(void* const* d_in, const int* in_sizes, int n_in,
                              void* d_out, int out_size, void* d_ws, size_t ws_size,
                              hipStream_t stream) {
    const int*   target = (const int*)  d_in[0];
    const float* enc    = (const float*)d_in[1];
    const float* emb    = (const float*)d_in[2];
    const float* w_ih   = (const float*)d_in[3];
    const float* w_hh   = (const float*)d_in[4];
    const float* b_ih   = (const float*)d_in[5];
    const float* b_hh   = (const float*)d_in[6];
    const float* lin_w  = (const float*)d_in[7];
    const float* lin_b  = (const float*)d_in[8];
    float* out1 = (float*)d_out;                       // log_probs  (B,T,V)
    float* out2 = out1 + (size_t)BB * TT * VV;         // decoder_logits (B,T,V)

    char* w = (char*)d_ws;
    float* h    = (float*)w;            w += BB * HH * 4;
    u16*   h_hi = (u16*)w;              w += BB * HH * 2;
    u16*   h_lo = (u16*)w;              w += BB * HH * 2;
    u16*   e_hi = (u16*)w;              w += BB * HH * 2;
    u16*   e_lo = (u16*)w;              w += BB * HH * 2;
    float* gi   = (float*)w;            w += BB * GG * 4;
    float* gh   = (float*)w;            w += BB * GG * 4;
    float* row_lse = (float*)w;         w += BB * TT * 4;

    init_kernel<<<BB, 256, 0, stream>>>(target, enc, emb, h, h_hi, h_lo, e_hi, e_lo);

    const int NB_G = GG / 64;                 // 48
    const int NB_V = (VV + 63) / 64;          // 786

    for (int t = 0; t < TT; ++t) {
        dim3 gg(NB_G, 2);
        gemm_gates_kernel<<<gg, 256, 0, stream>>>(e_hi, e_lo, h_hi, h_lo,
                                                  w_ih, w_hh, b_ih, b_hh, gi, gh);
        gate_kernel<<<(BB * HH) / 256, 256, 0, stream>>>(gi, gh, h, h_hi, h_lo);
        gemm_logits_kernel<<<NB_V, 256, 0, stream>>>(h_hi, h_lo, lin_w, lin_b,
                                                     out2 + (size_t)t * VV);
        argmax_kernel<<<BB, 256, 0, stream>>>(out2 + (size_t)t * VV, emb, t,
                                              row_lse, e_hi, e_lo);
    }
    logsoftmax_kernel<<<BB * TT, 256, 0, stream>>>(out2, row_lse, out1);
}

// Round 2
// 1719.025 us; speedup vs baseline: 1.4136x; 1.4136x over previous
//
#include <hip/hip_runtime.h>
#include <hip/hip_bf16.h>
#include <stdint.h>

#define BB 64
#define HH 1024
#define VV 50257
#define TT 7
#define GG 3072     // 3*HH
#define NT_V 3142   // ceil(VV/16)
#define NT_G 192    // GG/16

typedef __attribute__((ext_vector_type(8))) short bf16x8;
typedef __attribute__((ext_vector_type(4))) float f32x4;
typedef unsigned short u16;
typedef unsigned int u32;

__device__ __forceinline__ u16 rne_bf16(float f) {
    union { float f; u32 u; } v; v.f = f;
    u32 u = v.u + 0x7FFFu + ((v.u >> 16) & 1u);
    return (u16)(u >> 16);
}
// split f into hi (truncated bf16) + lo (rne bf16 of residual); hi+lo == f to ~2^-17|f|
__device__ __forceinline__ void split2(float f, u16 &hi, u16 &lo) {
    union { float f; u32 u; } v; v.f = f;
    union { u32 u; float f; } hv; hv.u = v.u & 0xFFFF0000u;
    hi = (u16)(v.u >> 16);
    lo = rne_bf16(f - hv.f);
}

// Packed-plane layouts (bf16 bits, u16):
//   W plane:  idx = ((ct*32 + kb)*64 + lane)*8 + j   lane=(q<<4)|l16; col=ct*16+l16; k=kb*32+q*8+j
//   A plane:  idx = ((kb*4 + mt)*64 + lane)*8 + j    m=mt*16+l16;     k=kb*32+q*8+j
// So every wave load is lane*16B within a contiguous 1KB tile => perfectly coalesced.

// ================== pack kernel: fp32 W (N x 1024 row-major) -> hi/lo planes ==================
__global__ __launch_bounds__(256) void pack_w_kernel(const float* __restrict__ W, int N,
                                                     u16* __restrict__ hi, u16* __restrict__ lo) {
    __shared__ float lds[16][260];
    const int ct = blockIdx.x, kg = blockIdx.y;      // 16 cols x 256 k per block
    const int t = threadIdx.x;
    {   // phase 1: coalesced global -> LDS (16 rows x 256B segments per iter)
        const int r = t >> 4, c = t & 15;
        const int col = ct * 16 + r;
        const float* src = W + (size_t)col * HH + kg * 256;
#pragma unroll
        for (int i = 0; i < 4; ++i) {
            f32x4 v = (f32x4){0.f, 0.f, 0.f, 0.f};
            if (col < N) v = *(const f32x4*)(src + i * 64 + c * 4);
            int x = i * 64 + c * 4;
            lds[r][x + 0] = v[0]; lds[r][x + 1] = v[1];
            lds[r][x + 2] = v[2]; lds[r][x + 3] = v[3];
        }
    }
    __syncthreads();
    // phase 2: LDS -> packed planes, fully coalesced 16B/lane stores
#pragma unroll
    for (int rep = 0; rep < 2; ++rep) {
        int o = t + rep * 256;
        int tau = o >> 6, lam = o & 63;
        int q = lam >> 4, rr = lam & 15;
        int kl = tau * 32 + q * 8;
        bf16x8 hv, lv;
#pragma unroll
        for (int j = 0; j < 8; ++j) {
            u16 h, l; split2(lds[rr][kl + j], h, l);
            hv[j] = (short)h; lv[j] = (short)l;
        }
        size_t unit = (size_t)(ct * 32 + kg * 8 + tau) * 64 + lam;   // bf16x8 units
        ((bf16x8*)hi)[unit] = hv;
        ((bf16x8*)lo)[unit] = lv;
    }
}

// ================== packed bf16x3 GEMM body ==================
__device__ __forceinline__ void gemm_packed(
    const u16* __restrict__ Ahi, const u16* __restrict__ Alo,
    const u16* __restrict__ Bhi, const u16* __restrict__ Blo,
    const float* __restrict__ bias, float* __restrict__ C,
    int ct, int N, size_t ldc)
{
    const int lane = threadIdx.x & 63;
    const int q = lane >> 4, l16 = lane & 15;

    const bf16x8* __restrict__ bh = (const bf16x8*)Bhi + (size_t)ct * 2048 + lane;
    const bf16x8* __restrict__ bl = (const bf16x8*)Blo + (size_t)ct * 2048 + lane;
    const bf16x8* __restrict__ ah = (const bf16x8*)Ahi + lane;
    const bf16x8* __restrict__ al = (const bf16x8*)Alo + lane;

    f32x4 acc[4];
#pragma unroll
    for (int mt = 0; mt < 4; ++mt) acc[mt] = (f32x4){0.f, 0.f, 0.f, 0.f};

#pragma unroll 2
    for (int kb = 0; kb < 32; ++kb) {
        bf16x8 bhv = bh[kb * 64];
        bf16x8 blv = bl[kb * 64];
#pragma unroll
        for (int mt = 0; mt < 4; ++mt) {
            bf16x8 ahv = ah[(kb * 4 + mt) * 64];
            bf16x8 alv = al[(kb * 4 + mt) * 64];
            acc[mt] = __builtin_amdgcn_mfma_f32_16x16x32_bf16(ahv, bhv, acc[mt], 0, 0, 0);
            acc[mt] = __builtin_amdgcn_mfma_f32_16x16x32_bf16(alv, bhv, acc[mt], 0, 0, 0);
            acc[mt] = __builtin_amdgcn_mfma_f32_16x16x32_bf16(ahv, blv, acc[mt], 0, 0, 0);
        }
    }

    const int col = ct * 16 + l16;
    if (col < N) {
        float bv = bias[col];
#pragma unroll
        for (int mt = 0; mt < 4; ++mt)
#pragma unroll
            for (int r = 0; r < 4; ++r)
                C[(size_t)(mt * 16 + q * 4 + r) * ldc + col] = acc[mt][r] + bv;
    }
}

__global__ __launch_bounds__(256) void gemm_logits_p_kernel(
    const u16* __restrict__ h_hp, const u16* __restrict__ h_lp,
    const u16* __restrict__ wv_hi, const u16* __restrict__ wv_lo,
    const float* __restrict__ lin_b, float* __restrict__ out_logits)
{
    int ct = blockIdx.x * 4 + (threadIdx.x >> 6);
    if (ct >= NT_V) return;
    gemm_packed(h_hp, h_lp, wv_hi, wv_lo, lin_b, out_logits, ct, VV, (size_t)TT * VV);
}

__global__ __launch_bounds__(64) void gemm_gates_p_kernel(
    const u16* __restrict__ e_hp, const u16* __restrict__ e_lp,
    const u16* __restrict__ h_hp, const u16* __restrict__ h_lp,
    const u16* __restrict__ wih_hi, const u16* __restrict__ wih_lo,
    const u16* __restrict__ whh_hi, const u16* __restrict__ whh_lo,
    const float* __restrict__ b_ih, const float* __restrict__ b_hh,
    float* __restrict__ gi, float* __restrict__ gh)
{
    int ct = blockIdx.x;
    if (blockIdx.y == 0) gemm_packed(e_hp, e_lp, wih_hi, wih_lo, b_ih, gi, ct, GG, GG);
    else                 gemm_packed(h_hp, h_lp, whh_hi, whh_lo, b_hh, gh, ct, GG, GG);
}

// packed A-plane u16 offset for element (b, k)
__device__ __forceinline__ size_t apack_off(int b, int k) {
    int kb = k >> 5, q = (k >> 3) & 3, joff = k & 7;
    int mt = b >> 4, l16 = b & 15;
    return ((size_t)(kb * 4 + mt) * 64 + (q * 16 + l16)) * 8 + joff;
}

// ================== init: h = enc[0]; e = relu(emb[target[:,0]]) (packed) ==================
__global__ void init_p_kernel(const int* __restrict__ target, const float* __restrict__ enc,
                              const float* __restrict__ emb,
                              float* __restrict__ h, u16* __restrict__ h_hp, u16* __restrict__ h_lp,
                              u16* __restrict__ e_hp, u16* __restrict__ e_lp) {
    int b = blockIdx.x;
    int x0 = target[b * TT];
    for (int k = threadIdx.x; k < HH; k += blockDim.x) {
        size_t po = apack_off(b, k);
        float hv = enc[b * HH + k];
        h[b * HH + k] = hv;
        u16 hh, hl; split2(hv, hh, hl);
        h_hp[po] = hh; h_lp[po] = hl;
        float e = emb[(size_t)x0 * HH + k];
        e = e > 0.f ? e : 0.f;
        u16 eh, el; split2(e, eh, el);
        e_hp[po] = eh; e_lp[po] = el;
    }
}

// ================== GRU gating (packed h out) ==================
__global__ void gate_p_kernel(const float* __restrict__ gi, const float* __restrict__ gh,
                              float* __restrict__ h, u16* __restrict__ h_hp, u16* __restrict__ h_lp) {
    int idx = blockIdx.x * blockDim.x + threadIdx.x;
    int b = idx >> 10, j = idx & 1023;
    float ir = gi[b * GG + j], iz = gi[b * GG + 1024 + j], in_ = gi[b * GG + 2048 + j];
    float hr = gh[b * GG + j], hz = gh[b * GG + 1024 + j], hn = gh[b * GG + 2048 + j];
    float r = 1.f / (1.f + expf(-(ir + hr)));
    float z = 1.f / (1.f + expf(-(iz + hz)));
    float n = tanhf(in_ + r * hn);
    float hold = h[b * HH + j];
    float hnew = (1.f - z) * n + z * hold;
    h[b * HH + j] = hnew;
    u16 hh, hl; split2(hnew, hh, hl);
    size_t po = apack_off(b, j);
    h_hp[po] = hh; h_lp[po] = hl;
}

// ================== argmax + lse + next-embedding gather (packed e out) ==================
__global__ __launch_bounds__(256) void argmax_p_kernel(
    const float* __restrict__ logits_t, const float* __restrict__ emb,
    int t, float* __restrict__ row_lse, u16* __restrict__ e_hp, u16* __restrict__ e_lp)
{
    __shared__ float sm[256], ss[256];
    __shared__ int sbi[256];
    int b = blockIdx.x, tid = threadIdx.x;
    const float* row = logits_t + (size_t)b * (TT * (size_t)VV);

    float m = -INFINITY, s = 0.f; int bi = 0x7fffffff;
    for (int v = tid; v < VV; v += 256) {
        float x = row[v];
        if (x > m) { s = s * expf(m - x) + 1.f; m = x; bi = v; }
        else       { s += expf(x - m); }
    }
    sm[tid] = m; ss[tid] = s; sbi[tid] = bi;
    __syncthreads();
    for (int off = 128; off > 0; off >>= 1) {
        if (tid < off) {
            float m1 = sm[tid], s1 = ss[tid]; int b1 = sbi[tid];
            float m2 = sm[tid + off], s2 = ss[tid + off]; int b2 = sbi[tid + off];
            float mn = fmaxf(m1, m2);
            float sn = s1 * expf(m1 - mn) + s2 * expf(m2 - mn);
            int bn = (m1 > m2) ? b1 : (m2 > m1) ? b2 : min(b1, b2);
            sm[tid] = mn; ss[tid] = sn; sbi[tid] = bn;
        }
        __syncthreads();
    }
    if (tid == 0) row_lse[b * TT + t] = sm[0] + logf(ss[0]);
    int xi = sbi[0];
    __syncthreads();
    for (int k = tid; k < HH; k += 256) {
        float e = emb[(size_t)xi * HH + k];
        e = e > 0.f ? e : 0.f;
        u16 eh, el; split2(e, eh, el);
        size_t po = apack_off(b, k);
        e_hp[po] = eh; e_lp[po] = el;
    }
}

// ================== final log_softmax ==================
__global__ void logsoftmax_kernel(const float* __restrict__ out2, const float* __restrict__ row_lse,
                                  float* __restrict__ out1) {
    int row = blockIdx.x;
    float lse = row_lse[row];
    const float* src = out2 + (size_t)row * VV;
    float* dst = out1 + (size_t)row * VV;
    const int NF4 = VV / 4;   // 12564
    for (int i = threadIdx.x; i < NF4; i += blockDim.x) {
        f32x4 v = *(const f32x4*)(src + i * 4);
        v[0] -= lse; v[1] -= lse; v[2] -= lse; v[3] -= lse;
        *(f32x4*)(dst + i * 4) = v;
    }
    if (threadIdx.x == 0) dst[VV - 1] = src[VV - 1] - lse;
}

// ======================================================================
// =================== round-1 fallback path (unpacked) =================
// ======================================================================
__global__ void init_kernel_fb(const int* __restrict__ target, const float* __restrict__ enc,
                               const float* __restrict__ emb,
                               float* __restrict__ h, u16* __restrict__ h_hi, u16* __restrict__ h_lo,
                               u16* __restrict__ e_hi, u16* __restrict__ e_lo) {
    int b = blockIdx.x;
    int x0 = target[b * TT];
    for (int k = threadIdx.x; k < HH; k += blockDim.x) {
        float hv = enc[b * HH + k];
        h[b * HH + k] = hv;
        u16 hh, hl; split2(hv, hh, hl);
        h_hi[b * HH + k] = hh; h_lo[b * HH + k] = hl;
        float e = emb[(size_t)x0 * HH + k];
        e = e > 0.f ? e : 0.f;
        u16 eh, el; split2(e, eh, el);
        e_hi[b * HH + k] = eh; e_lo[b * HH + k] = el;
    }
}

__device__ __forceinline__ void gemm_body_fb(
    const u16* __restrict__ Ahi, const u16* __restrict__ Alo,
    const float* __restrict__ W, const float* __restrict__ bias,
    float* __restrict__ C, int N, int ldc)
{
    const int wave = threadIdx.x >> 6;
    const int lane = threadIdx.x & 63;
    const int quad = lane >> 4;
    const int l16  = lane & 15;
    const int col  = blockIdx.x * 64 + wave * 16 + l16;
    const int colc = col < N ? col : N - 1;
    const float* __restrict__ Brow = W + (size_t)colc * HH;
    const int koff = quad * 8;
    f32x4 acc[4];
#pragma unroll
    for (int mt = 0; mt < 4; ++mt) acc[mt] = (f32x4){0.f, 0.f, 0.f, 0.f};
    for (int kb = 0; kb < HH; kb += 32) {
        const float* bp = Brow + kb + koff;
        f32x4 bv0 = *(const f32x4*)(bp);
        f32x4 bv1 = *(const f32x4*)(bp + 4);
        bf16x8 bhi, blo;
#pragma unroll
        for (int j = 0; j < 8; ++j) {
            float f = j < 4 ? bv0[j] : bv1[j - 4];
            union { float f; u32 u; } c; c.f = f;
            union { u32 u; float f; } hf; hf.u = c.u & 0xFFFF0000u;
            bhi[j] = (short)(c.u >> 16);
            blo[j] = (short)rne_bf16(f - hf.f);
        }
#pragma unroll
        for (int mt = 0; mt < 4; ++mt) {
            const size_t aoff = (size_t)(mt * 16 + l16) * HH + kb + koff;
            bf16x8 ahi = *(const bf16x8*)(Ahi + aoff);
            bf16x8 alo = *(const bf16x8*)(Alo + aoff);
            acc[mt] = __builtin_amdgcn_mfma_f32_16x16x32_bf16(ahi, bhi, acc[mt], 0, 0, 0);
            acc[mt] = __builtin_amdgcn_mfma_f32_16x16x32_bf16(alo, bhi, acc[mt], 0, 0, 0);
            acc[mt] = __builtin_amdgcn_mfma_f32_16x16x32_bf16(ahi, blo, acc[mt], 0, 0, 0);
        }
    }
    if (col < N) {
        float bv = bias[col];
#pragma unroll
        for (int mt = 0; mt < 4; ++mt)
#pragma unroll
            for (int r = 0; r < 4; ++r)
                C[(size_t)(mt * 16 + quad * 4 + r) * ldc + col] = acc[mt][r] + bv;
    }
}

__global__ __launch_bounds__(256) void gemm_gates_kernel_fb(
    const u16* __restrict__ e_hi, const u16* __restrict__ e_lo,
    const u16* __restrict__ h_hi, const u16* __restrict__ h_lo,
    const float* __restrict__ w_ih, const float* __restrict__ w_hh,
    const float* __restrict__ b_ih, const float* __restrict__ b_hh,
    float* __restrict__ gi, float* __restrict__ gh)
{
    if (blockIdx.y == 0) gemm_body_fb(e_hi, e_lo, w_ih, b_ih, gi, GG, GG);
    else                 gemm_body_fb(h_hi, h_lo, w_hh, b_hh, gh, GG, GG);
}

__global__ __launch_bounds__(256) void gemm_logits_kernel_fb(
    const u16* __restrict__ h_hi, const u16* __restrict__ h_lo,
    const float* __restrict__ lin_w, const float* __restrict__ lin_b,
    float* __restrict__ out_logits)
{
    gemm_body_fb(h_hi, h_lo, lin_w, lin_b, out_logits, VV, TT * VV);
}

__global__ void gate_kernel_fb(const float* __restrict__ gi, const float* __restrict__ gh,
                               float* __restrict__ h, u16* __restrict__ h_hi, u16* __restrict__ h_lo) {
    int idx = blockIdx.x * blockDim.x + threadIdx.x;
    int b = idx >> 10, j = idx & 1023;
    float ir = gi[b * GG + j], iz = gi[b * GG + 1024 + j], in_ = gi[b * GG + 2048 + j];
    float hr = gh[b * GG + j], hz = gh[b * GG + 1024 + j], hn = gh[b * GG + 2048 + j];
    float r = 1.f / (1.f + expf(-(ir + hr)));
    float z = 1.f / (1.f + expf(-(iz + hz)));
    float n = tanhf(in_ + r * hn);
    float hold = h[b * HH + j];
    float hnew = (1.f - z) * n + z * hold;
    h[b * HH + j] = hnew;
    u16 hh, hl; split2(hnew, hh, hl);
    h_hi[b * HH + j] = hh; h_lo[b * HH + j] = hl;
}

__global__ __launch_bounds__(256) void argmax_kernel_fb(
    const float* __restrict__ logits_t, const float* __restrict__ emb,
    int t, float* __restrict__ row_lse, u16* __restrict__ e_hi, u16* __restrict__ e_lo)
{
    __shared__ float sm[256], ss[256];
    __shared__ int sbi[256];
    int b = blockIdx.x, tid = threadIdx.x;
    const float* row = logits_t + (size_t)b * (TT * (size_t)VV);
    float m = -INFINITY, s = 0.f; int bi = 0x7fffffff;
    for (int v = tid; v < VV; v += 256) {
        float x = row[v];
        if (x > m) { s = s * expf(m - x) + 1.f; m = x; bi = v; }
        else       { s += expf(x - m); }
    }
    sm[tid] = m; ss[tid] = s; sbi[tid] = bi;
    __syncthreads();
    for (int off = 128; off > 0; off >>= 1) {
        if (tid < off) {
            float m1 = sm[tid], s1 = ss[tid]; int b1 = sbi[tid];
            float m2 = sm[tid + off], s2 = ss[tid + off]; int b2 = sbi[tid + off];
            float mn = fmaxf(m1, m2);
            float sn = s1 * expf(m1 - mn) + s2 * expf(m2 - mn);
            int bn = (m1 > m2) ? b1 : (m2 > m1) ? b2 : min(b1, b2);
            sm[tid] = mn; ss[tid] = sn; sbi[tid] = bn;
        }
        __syncthreads();
    }
    if (tid == 0) row_lse[b * TT + t] = sm[0] + logf(ss[0]);
    int xi = sbi[0];
    __syncthreads();
    for (int k = tid; k < HH; k += 256) {
        float e = emb[(size_t)xi * HH + k];
        e = e > 0.f ? e : 0.f;
        u16 eh, el; split2(e, eh, el);
        e_hi[b * HH + k] = eh; e_lo[b * HH + k] = el;
    }
}

// ======================================================================
extern "C" void kernel_launch(void* const* d_in, const int* in_sizes, int n_in,
                              void* d_out, int out_size, void* d_ws, size_t ws_size,
                              hipStream_t stream) {
    const int*   target = (const int*)  d_in[0];
    const float* enc    = (const float*)d_in[1];
    const float* emb    = (const float*)d_in[2];
    const float* w_ih   = (const float*)d_in[3];
    const float* w_hh   = (const float*)d_in[4];
    const float* b_ih   = (const float*)d_in[5];
    const float* b_hh   = (const float*)d_in[6];
    const float* lin_w  = (const float*)d_in[7];
    const float* lin_b  = (const float*)d_in[8];
    float* out1 = (float*)d_out;                       // log_probs  (B,T,V)
    float* out2 = out1 + (size_t)BB * TT * VV;         // decoder_logits (B,T,V)

    const size_t SZ_WV = (size_t)NT_V * 16384;         // u16 per V plane
    const size_t SZ_WG = (size_t)NT_G * 16384;         // u16 per gates plane
    const size_t need = 2 * SZ_WV * 2 + 4 * SZ_WG * 2  // packed W planes (bytes)
                      + BB * HH * 4                    // h
                      + 4 * BB * HH * 2                // packed A planes
                      + 2 * BB * GG * 4                // gi, gh
                      + BB * TT * 4 + 1024;

    if (ws_size >= need) {
        char* w = (char*)d_ws;
        u16* wv_hi = (u16*)w;  w += SZ_WV * 2;
        u16* wv_lo = (u16*)w;  w += SZ_WV * 2;
        u16* wih_hi = (u16*)w; w += SZ_WG * 2;
        u16* wih_lo = (u16*)w; w += SZ_WG * 2;
        u16* whh_hi = (u16*)w; w += SZ_WG * 2;
        u16* whh_lo = (u16*)w; w += SZ_WG * 2;
        float* h   = (float*)w; w += BB * HH * 4;
        u16* h_hp  = (u16*)w;  w += BB * HH * 2;
        u16* h_lp  = (u16*)w;  w += BB * HH * 2;
        u16* e_hp  = (u16*)w;  w += BB * HH * 2;
        u16* e_lp  = (u16*)w;  w += BB * HH * 2;
        float* gi  = (float*)w; w += BB * GG * 4;
        float* gh  = (float*)w; w += BB * GG * 4;
        float* row_lse = (float*)w;

        // one-time packs
        pack_w_kernel<<<dim3(NT_V, 4), 256, 0, stream>>>(lin_w, VV, wv_hi, wv_lo);
        pack_w_kernel<<<dim3(NT_G, 4), 256, 0, stream>>>(w_ih, GG, wih_hi, wih_lo);
        pack_w_kernel<<<dim3(NT_G, 4), 256, 0, stream>>>(w_hh, GG, whh_hi, whh_lo);
        init_p_kernel<<<BB, 256, 0, stream>>>(target, enc, emb, h, h_hp, h_lp, e_hp, e_lp);

        for (int t = 0; t < TT; ++t) {
            gemm_gates_p_kernel<<<dim3(NT_G, 2), 64, 0, stream>>>(
                e_hp, e_lp, h_hp, h_lp, wih_hi, wih_lo, whh_hi, whh_lo, b_ih, b_hh, gi, gh);
            gate_p_kernel<<<(BB * HH) / 256, 256, 0, stream>>>(gi, gh, h, h_hp, h_lp);
            gemm_logits_p_kernel<<<(NT_V + 3) / 4, 256, 0, stream>>>(
                h_hp, h_lp, wv_hi, wv_lo, lin_b, out2 + (size_t)t * VV);
            argmax_p_kernel<<<BB, 256, 0, stream>>>(out2 + (size_t)t * VV, emb, t,
                                                    row_lse, e_hp, e_lp);
        }
        logsoftmax_kernel<<<BB * TT, 256, 0, stream>>>(out2, row_lse, out1);
    } else {
        // -------- fallback: round-1 path (~3.6 MB ws) --------
        char* w = (char*)d_ws;
        float* h    = (float*)w;            w += BB * HH * 4;
        u16*   h_hi = (u16*)w;              w += BB * HH * 2;
        u16*   h_lo = (u16*)w;              w += BB * HH * 2;
        u16*   e_hi = (u16*)w;              w += BB * HH * 2;
        u16*   e_lo = (u16*)w;              w += BB * HH * 2;
        float* gi   = (float*)w;            w += BB * GG * 4;
        float* gh   = (float*)w;            w += BB * GG * 4;
        float* row_lse = (float*)w;

        init_kernel_fb<<<BB, 256, 0, stream>>>(target, enc, emb, h, h_hi, h_lo, e_hi, e_lo);
        const int NB_G = GG / 64;
        const int NB_V = (VV + 63) / 64;
        for (int t = 0; t < TT; ++t) {
            gemm_gates_kernel_fb<<<dim3(NB_G, 2), 256, 0, stream>>>(
                e_hi, e_lo, h_hi, h_lo, w_ih, w_hh, b_ih, b_hh, gi, gh);
            gate_kernel_fb<<<(BB * HH) / 256, 256, 0, stream>>>(gi, gh, h, h_hi, h_lo);
            gemm_logits_kernel_fb<<<NB_V, 256, 0, stream>>>(h_hi, h_lo, lin_w, lin_b,
                                                            out2 + (size_t)t * VV);
            argmax_kernel_fb<<<BB, 256, 0, stream>>>(out2 + (size_t)t * VV, emb, t,
                                                     row_lse, e_hi, e_lo);
        }
        logsoftmax_kernel<<<BB * TT, 256, 0, stream>>>(out2, row_lse, out1);
    }
}